// Round 1
// baseline (1617.012 us; speedup 1.0000x reference)
//
#include <hip/hip_runtime.h>

typedef __attribute__((ext_vector_type(4))) float f32x4;
typedef __attribute__((ext_vector_type(8))) short short8;

#define DEVI static __device__ __forceinline__

DEVI unsigned short f2bf(float f) {
  unsigned int u = __float_as_uint(f);
  u += 0x7FFFu + ((u >> 16) & 1u);
  return (unsigned short)(u >> 16);
}
DEVI float bf2f(unsigned short s) { return __uint_as_float(((unsigned int)s) << 16); }
DEVI unsigned int pack2(float lo, float hi) {
  return ((unsigned int)f2bf(hi) << 16) | (unsigned int)f2bf(lo);
}

// ---------------- f32 -> bf16 convert (weights) ----------------
__global__ __launch_bounds__(256) void k_cvt_bf16(const float* __restrict__ src,
                                                  unsigned short* __restrict__ dst, int n4) {
  int i = blockIdx.x * 256 + threadIdx.x;
  if (i < n4) {
    float4 v = ((const float4*)src)[i];
    uint2 o; o.x = pack2(v.x, v.y); o.y = pack2(v.z, v.w);
    ((uint2*)dst)[i] = o;
  }
}

// ---------------- generic C[M,N] = A[M,K] * B[N,K]^T  (bf16 MFMA) -----------
// grid = (N/128, M/128), 256 threads. K = 2048 fixed. Optional fused epilogue:
// C = bf16( resid + relu(acc) ).
template <bool AF32, bool RES>
__global__ __launch_bounds__(256) void k_gemm_bt(const void* __restrict__ Ap,
                                                 const unsigned short* __restrict__ B,
                                                 unsigned short* __restrict__ C,
                                                 const float* __restrict__ resid, int N) {
  constexpr int K = 2048;
  __shared__ unsigned short lA[128 * 64];
  __shared__ unsigned short lB[128 * 64];
  const int tid = threadIdx.x;
  const int lane = tid & 63;
  const int wave = tid >> 6;
  const int wr = wave >> 1, wc = wave & 1;
  const long mBase = (long)blockIdx.y * 128;
  const long nBase = (long)blockIdx.x * 128;

  f32x4 acc[4][4] = {};

  for (int k0 = 0; k0 < K; k0 += 64) {
    __syncthreads();
#pragma unroll
    for (int i = 0; i < 4; i++) {
      int seg = i * 256 + tid;  // 0..1023 : (row, 16B-chunk)
      int row = seg >> 3;
      int kc = seg & 7;
      int slot = kc ^ (row & 7);
      if constexpr (AF32) {
        const float* g = (const float*)Ap + (mBase + row) * (long)K + k0 + kc * 8;
        float4 u = *(const float4*)g;
        float4 v = *(const float4*)(g + 4);
        uint4 w;
        w.x = pack2(u.x, u.y); w.y = pack2(u.z, u.w);
        w.z = pack2(v.x, v.y); w.w = pack2(v.z, v.w);
        *(uint4*)&lA[row * 64 + slot * 8] = w;
      } else {
        const unsigned short* g = (const unsigned short*)Ap + (mBase + row) * (long)K + k0 + kc * 8;
        *(uint4*)&lA[row * 64 + slot * 8] = *(const uint4*)g;
      }
      const unsigned short* gb = B + (nBase + row) * (long)K + k0 + kc * 8;
      *(uint4*)&lB[row * 64 + slot * 8] = *(const uint4*)gb;
    }
    __syncthreads();
#pragma unroll
    for (int kb = 0; kb < 2; kb++) {
      short8 af[4], bfr[4];
#pragma unroll
      for (int mt = 0; mt < 4; mt++) {
        int row = wr * 64 + mt * 16 + (lane & 15);
        int slot = (kb * 4 + (lane >> 4)) ^ (row & 7);
        af[mt] = *(const short8*)&lA[row * 64 + slot * 8];
      }
#pragma unroll
      for (int nt = 0; nt < 4; nt++) {
        int row = wc * 64 + nt * 16 + (lane & 15);
        int slot = (kb * 4 + (lane >> 4)) ^ (row & 7);
        bfr[nt] = *(const short8*)&lB[row * 64 + slot * 8];
      }
#pragma unroll
      for (int mt = 0; mt < 4; mt++)
#pragma unroll
        for (int nt = 0; nt < 4; nt++)
          acc[mt][nt] = __builtin_amdgcn_mfma_f32_16x16x32_bf16(af[mt], bfr[nt], acc[mt][nt], 0, 0, 0);
    }
  }
  // epilogue: D[row = (lane>>4)*4+j][col = lane&15] per 16x16 tile
#pragma unroll
  for (int mt = 0; mt < 4; mt++) {
#pragma unroll
    for (int nt = 0; nt < 4; nt++) {
#pragma unroll
      for (int j = 0; j < 4; j++) {
        long row = mBase + wr * 64 + mt * 16 + (lane >> 4) * 4 + j;
        long col = nBase + wc * 64 + nt * 16 + (lane & 15);
        float v = acc[mt][nt][j];
        if constexpr (RES) v = resid[row * (long)N + col] + fmaxf(v, 0.0f);
        C[row * (long)N + col] = f2bf(v);
      }
    }
  }
}

// ---------------- per-group inner attention: S=fe*fe^T, softmax, agg=att*feat
// grid = 320 (one block per (class,unlabel) group), 256 threads.
__global__ __launch_bounds__(256) void k_attn_inner(const unsigned short* __restrict__ fe,
                                                    const float* __restrict__ topk,
                                                    unsigned short* __restrict__ agg) {
  __shared__ unsigned short attb[128 * 136];  // att (bf16), padded stride
  __shared__ unsigned short featc[128 * 64];  // feat column-chunk (bf16)
  __shared__ float redmax[2 * 128];
  __shared__ float redsum[2 * 128];
  const int tid = threadIdx.x;
  const int lane = tid & 63;
  const int wave = tid >> 6;
  const int wr = wave >> 1, wc = wave & 1;
  const int g = blockIdx.x;
  const unsigned short* feG = fe + (long)g * 128 * 256;

  // ---- Phase 1: S tile (this wave: rows wr*64.., cols wc*64..), frags from global
  f32x4 s[4][4] = {};
#pragma unroll
  for (int kb = 0; kb < 8; kb++) {
    short8 af[4], bfr[4];
#pragma unroll
    for (int mt = 0; mt < 4; mt++) {
      int row = wr * 64 + mt * 16 + (lane & 15);
      af[mt] = *(const short8*)(feG + row * 256 + kb * 32 + (lane >> 4) * 8);
    }
#pragma unroll
    for (int nt = 0; nt < 4; nt++) {
      int row = wc * 64 + nt * 16 + (lane & 15);
      bfr[nt] = *(const short8*)(feG + row * 256 + kb * 32 + (lane >> 4) * 8);
    }
#pragma unroll
    for (int mt = 0; mt < 4; mt++)
#pragma unroll
      for (int nt = 0; nt < 4; nt++)
        s[mt][nt] = __builtin_amdgcn_mfma_f32_16x16x32_bf16(af[mt], bfr[nt], s[mt][nt], 0, 0, 0);
  }

  // ---- softmax over columns (axis l). value(mt,nt,j): row=wr*64+mt*16+(lane>>4)*4+j,
  //      col=wc*64+nt*16+(lane&15)
  const float cexp = 0.0625f * 1.44269504088896f;  // scale * log2(e)
  float mx[4][4];
#pragma unroll
  for (int mt = 0; mt < 4; mt++) {
#pragma unroll
    for (int j = 0; j < 4; j++) {
      float m = fmaxf(fmaxf(s[mt][0][j], s[mt][1][j]), fmaxf(s[mt][2][j], s[mt][3][j]));
#pragma unroll
      for (int d = 1; d < 16; d <<= 1) m = fmaxf(m, __shfl_xor(m, d, 64));
      mx[mt][j] = m;
      int r = wr * 64 + mt * 16 + (lane >> 4) * 4 + j;
      if ((lane & 15) == 0) redmax[wc * 128 + r] = m;
    }
  }
  __syncthreads();
#pragma unroll
  for (int mt = 0; mt < 4; mt++) {
#pragma unroll
    for (int j = 0; j < 4; j++) {
      int r = wr * 64 + mt * 16 + (lane >> 4) * 4 + j;
      float M = fmaxf(redmax[r], redmax[128 + r]);
      float sm = 0.f;
#pragma unroll
      for (int nt = 0; nt < 4; nt++) {
        float p = exp2f((s[mt][nt][j] - M) * cexp);
        s[mt][nt][j] = p;
        sm += p;
      }
#pragma unroll
      for (int d = 1; d < 16; d <<= 1) sm += __shfl_xor(sm, d, 64);
      if ((lane & 15) == 0) redsum[wc * 128 + r] = sm;
    }
  }
  __syncthreads();
#pragma unroll
  for (int mt = 0; mt < 4; mt++) {
#pragma unroll
    for (int j = 0; j < 4; j++) {
      int r = wr * 64 + mt * 16 + (lane >> 4) * 4 + j;
      float inv = 1.0f / (redsum[r] + redsum[128 + r]);
#pragma unroll
      for (int nt = 0; nt < 4; nt++) {
        int c = wc * 64 + nt * 16 + (lane & 15);
        attb[r * 136 + c] = f2bf(s[mt][nt][j] * inv);
      }
    }
  }

  // ---- Phase 2: agg = att @ feat, 64-column chunks. wave -> rows wave*32..+31
  for (int ch = 0; ch < 32; ch++) {
    __syncthreads();  // also makes attb visible on first iteration
#pragma unroll
    for (int i = 0; i < 4; i++) {
      int seg = i * 256 + tid;
      int row = seg >> 3, kc = seg & 7;
      const float* gp = topk + ((long)g * 128 + row) * 2048 + ch * 64 + kc * 8;
      float4 u = *(const float4*)gp;
      float4 v = *(const float4*)(gp + 4);
      uint4 w;
      w.x = pack2(u.x, u.y); w.y = pack2(u.z, u.w);
      w.z = pack2(v.x, v.y); w.w = pack2(v.z, v.w);
      *(uint4*)&featc[row * 64 + kc * 8] = w;
    }
    __syncthreads();
    f32x4 c[2][4] = {};
#pragma unroll
    for (int kb = 0; kb < 4; kb++) {
      short8 af2[2], bf2v[4];
#pragma unroll
      for (int mt = 0; mt < 2; mt++) {
        int r = wave * 32 + mt * 16 + (lane & 15);
        af2[mt] = *(const short8*)&attb[r * 136 + kb * 32 + (lane >> 4) * 8];
      }
#pragma unroll
      for (int nt = 0; nt < 4; nt++) {
        int col = nt * 16 + (lane & 15);
        union { unsigned short u[8]; short8 v; } bb;
#pragma unroll
        for (int j = 0; j < 8; j++)
          bb.u[j] = featc[(kb * 32 + (lane >> 4) * 8 + j) * 64 + col];
        bf2v[nt] = bb.v;
      }
#pragma unroll
      for (int mt = 0; mt < 2; mt++)
#pragma unroll
        for (int nt = 0; nt < 4; nt++)
          c[mt][nt] = __builtin_amdgcn_mfma_f32_16x16x32_bf16(af2[mt], bf2v[nt], c[mt][nt], 0, 0, 0);
    }
#pragma unroll
    for (int mt = 0; mt < 2; mt++)
#pragma unroll
      for (int nt = 0; nt < 4; nt++)
#pragma unroll
        for (int j = 0; j < 4; j++) {
          long row = (long)g * 128 + wave * 32 + mt * 16 + (lane >> 4) * 4 + j;
          int col = ch * 64 + nt * 16 + (lane & 15);
          agg[row * 2048 + col] = f2bf(c[mt][nt][j]);
        }
  }
}

// ---------------- per-class: pe = protos*Wi2^T ; att2 = softmax(pe*fae^T/16) --
// grid = 20, 256 threads.
__global__ __launch_bounds__(256) void k_att2(const float* __restrict__ protos,
                                              const float* __restrict__ wi2,
                                              const unsigned short* __restrict__ fae,
                                              float* __restrict__ att2) {
  __shared__ float pe[5 * 256];
  __shared__ float rbuf[5 * 4];
  __shared__ float rbuf2[5 * 4];
  const int tid = threadIdx.x;
  const int n = blockIdx.x;
#pragma unroll
  for (int i = 0; i < 5; i++) {
    int idx = i * 256 + tid;  // 0..1279
    int p = idx >> 8, o = idx & 255;
    const float* pr = protos + ((long)n * 5 + p) * 2048;
    const float* wrow = wi2 + (long)o * 2048;
    float acc = 0.f;
    for (int c = 0; c < 2048; c += 4) {
      float4 a = *(const float4*)(pr + c);
      float4 b = *(const float4*)(wrow + c);
      acc += a.x * b.x + a.y * b.y + a.z * b.z + a.w * b.w;
    }
    pe[p * 256 + o] = acc;
  }
  __syncthreads();

  float lg[5][8];
#pragma unroll
  for (int i = 0; i < 8; i++) {
    int m = i * 256 + tid;
    const unsigned short* fr = fae + ((long)n * 2048 + m) * 256;
    float a[5] = {0.f, 0.f, 0.f, 0.f, 0.f};
    for (int o = 0; o < 256; o += 8) {
      uint4 w = *(const uint4*)(fr + o);
      float f[8];
      f[0] = bf2f((unsigned short)(w.x & 0xffff)); f[1] = bf2f((unsigned short)(w.x >> 16));
      f[2] = bf2f((unsigned short)(w.y & 0xffff)); f[3] = bf2f((unsigned short)(w.y >> 16));
      f[4] = bf2f((unsigned short)(w.z & 0xffff)); f[5] = bf2f((unsigned short)(w.z >> 16));
      f[6] = bf2f((unsigned short)(w.w & 0xffff)); f[7] = bf2f((unsigned short)(w.w >> 16));
#pragma unroll
      for (int j = 0; j < 8; j++) {
        float fv = f[j];
#pragma unroll
        for (int p = 0; p < 5; p++) a[p] += fv * pe[p * 256 + o + j];
      }
    }
#pragma unroll
    for (int p = 0; p < 5; p++) lg[p][i] = a[p] * 0.0625f;
  }
  // softmax over all 2048 m per p
#pragma unroll
  for (int p = 0; p < 5; p++) {
    float v = lg[p][0];
#pragma unroll
    for (int i = 1; i < 8; i++) v = fmaxf(v, lg[p][i]);
#pragma unroll
    for (int d = 1; d < 64; d <<= 1) v = fmaxf(v, __shfl_xor(v, d, 64));
    if ((tid & 63) == 0) rbuf[p * 4 + (tid >> 6)] = v;
  }
  __syncthreads();
  float Mv[5];
#pragma unroll
  for (int p = 0; p < 5; p++)
    Mv[p] = fmaxf(fmaxf(rbuf[p * 4], rbuf[p * 4 + 1]), fmaxf(rbuf[p * 4 + 2], rbuf[p * 4 + 3]));
#pragma unroll
  for (int p = 0; p < 5; p++) {
    float sm = 0.f;
#pragma unroll
    for (int i = 0; i < 8; i++) {
      float e = exp2f((lg[p][i] - Mv[p]) * 1.44269504088896f);
      lg[p][i] = e;
      sm += e;
    }
#pragma unroll
    for (int d = 1; d < 64; d <<= 1) sm += __shfl_xor(sm, d, 64);
    if ((tid & 63) == 0) rbuf2[p * 4 + (tid >> 6)] = sm;
  }
  __syncthreads();
#pragma unroll
  for (int p = 0; p < 5; p++) {
    float tot = rbuf2[p * 4] + rbuf2[p * 4 + 1] + rbuf2[p * 4 + 2] + rbuf2[p * 4 + 3];
    float inv = 1.0f / tot;
#pragma unroll
    for (int i = 0; i < 8; i++)
      att2[((long)n * 5 + p) * 2048 + i * 256 + tid] = lg[p][i] * inv;
  }
}

// ---------------- un_protos = att2 @ fa ------------------------------------
// grid = (20, 4), 256 threads; each block: one class, 512 columns.
__global__ __launch_bounds__(256) void k_out(const float* __restrict__ att2,
                                             const unsigned short* __restrict__ feats,
                                             float* __restrict__ outp) {
  __shared__ float a2[5 * 2048];
  const int tid = threadIdx.x;
  const int n = blockIdx.x;
  const int chb = blockIdx.y;
  const float* src = att2 + (long)n * 5 * 2048;
#pragma unroll
  for (int i = 0; i < 10; i++) {
    int idx = i * 256 + tid;  // float4 index
    ((float4*)a2)[idx] = ((const float4*)src)[idx];
  }
  __syncthreads();
  int c0 = chb * 512 + tid * 2;
  const unsigned short* fa = feats + (long)n * 2048 * 2048 + c0;
  float acc[5][2] = {};
#pragma unroll 4
  for (int m = 0; m < 2048; m++) {
    unsigned int w = *(const unsigned int*)(fa + (long)m * 2048);
    float f0 = bf2f((unsigned short)(w & 0xffff));
    float f1 = bf2f((unsigned short)(w >> 16));
#pragma unroll
    for (int p = 0; p < 5; p++) {
      float a = a2[p * 2048 + m];
      acc[p][0] += a * f0;
      acc[p][1] += a * f1;
    }
  }
#pragma unroll
  for (int p = 0; p < 5; p++) {
    float* op = outp + ((long)n * 5 + p) * 2048 + c0;
    op[0] = acc[p][0];
    op[1] = acc[p][1];
  }
}

extern "C" void kernel_launch(void* const* d_in, const int* in_sizes, int n_in,
                              void* d_out, int out_size, void* d_ws, size_t ws_size,
                              hipStream_t stream) {
  const float* topk = (const float*)d_in[0];      // [20,16,128,2048]
  const float* protos = (const float*)d_in[1];    // [20,5,2048]
  const float* w1 = (const float*)d_in[2];        // [256,2048]
  const float* wt = (const float*)d_in[3];        // [2048,2048]
  const float* wi1 = (const float*)d_in[4];       // [256,2048]
  const float* wi2 = (const float*)d_in[5];       // [256,2048]
  float* outp = (float*)d_out;

  char* ws = (char*)d_ws;
  size_t off = 0;
  auto alloc = [&](size_t bytes) -> void* {
    void* p = ws + off;
    off += (bytes + 255) & ~(size_t)255;
    return p;
  };
  unsigned short* w1b = (unsigned short*)alloc((size_t)256 * 2048 * 2);
  unsigned short* wtb = (unsigned short*)alloc((size_t)2048 * 2048 * 2);
  unsigned short* wi1b = (unsigned short*)alloc((size_t)256 * 2048 * 2);
  unsigned short* fe = (unsigned short*)alloc((size_t)40960 * 256 * 2);
  unsigned short* agg = (unsigned short*)alloc((size_t)40960 * 2048 * 2);
  unsigned short* feats = (unsigned short*)alloc((size_t)40960 * 2048 * 2);
  unsigned short* fae = (unsigned short*)alloc((size_t)40960 * 256 * 2);
  float* att2 = (float*)alloc((size_t)20 * 5 * 2048 * 4);

  k_cvt_bf16<<<512, 256, 0, stream>>>(w1, w1b, 131072);
  k_cvt_bf16<<<4096, 256, 0, stream>>>(wt, wtb, 1048576);
  k_cvt_bf16<<<512, 256, 0, stream>>>(wi1, wi1b, 131072);

  // fe = feat @ W1^T   [40960,256]
  k_gemm_bt<true, false><<<dim3(2, 320), 256, 0, stream>>>(topk, w1b, fe, nullptr, 256);
  // att + agg per group
  k_attn_inner<<<320, 256, 0, stream>>>(fe, topk, agg);
  // feats = feat + relu(agg @ Wt^T)   [40960,2048]
  k_gemm_bt<false, true><<<dim3(16, 320), 256, 0, stream>>>(agg, wtb, feats, topk, 2048);
  // fae = feats @ Wi1^T   [40960,256]
  k_gemm_bt<false, false><<<dim3(2, 320), 256, 0, stream>>>(feats, wi1b, fae, nullptr, 256);
  // att2
  k_att2<<<20, 256, 0, stream>>>(protos, wi2, fae, att2);
  // un_protos = att2 @ fa
  k_out<<<dim3(20, 4), 256, 0, stream>>>(att2, feats, outp);
}

// Round 2
// 1032.466 us; speedup vs baseline: 1.5662x; 1.5662x over previous
//
#include <hip/hip_runtime.h>

typedef __attribute__((ext_vector_type(4))) float f32x4;
typedef __attribute__((ext_vector_type(8))) short short8;

#define DEVI static __device__ __forceinline__

DEVI unsigned short f2bf(float f) {
  unsigned int u = __float_as_uint(f);
  u += 0x7FFFu + ((u >> 16) & 1u);
  return (unsigned short)(u >> 16);
}
DEVI float bf2f(unsigned short s) { return __uint_as_float(((unsigned int)s) << 16); }
DEVI unsigned int pack2(float lo, float hi) {
  return ((unsigned int)f2bf(hi) << 16) | (unsigned int)f2bf(lo);
}

#define GL2LDS(gp, lp)                                                        \
  __builtin_amdgcn_global_load_lds(                                           \
      (const __attribute__((address_space(1))) void*)(const void*)(gp),       \
      (__attribute__((address_space(3))) void*)(void*)(lp), 16, 0, 0)

// ---------------- f32 -> bf16 convert ----------------
__global__ __launch_bounds__(256) void k_cvt_bf16(const float* __restrict__ src,
                                                  unsigned short* __restrict__ dst, int n4) {
  int i = blockIdx.x * 256 + threadIdx.x;
  if (i < n4) {
    float4 v = ((const float4*)src)[i];
    uint2 o; o.x = pack2(v.x, v.y); o.y = pack2(v.z, v.w);
    ((uint2*)dst)[i] = o;
  }
}

// ---------------- C[M,N] = A[M,K] * B[N,K]^T  (bf16 MFMA, global_load_lds) ---
// grid = (N/128, M/128), 256 threads, K=2048. RES: C = bf16(resid + relu(acc)).
template <bool RES>
__global__ __launch_bounds__(256) void k_gemm_bt(const unsigned short* __restrict__ A,
                                                 const unsigned short* __restrict__ B,
                                                 unsigned short* __restrict__ C,
                                                 const float* __restrict__ resid, int N) {
  constexpr int K = 2048;
  __shared__ unsigned short lA[128 * 64];
  __shared__ unsigned short lB[128 * 64];
  const int tid = threadIdx.x;
  const int lane = tid & 63;
  const int wave = tid >> 6;
  const int wr = wave >> 1, wc = wave & 1;
  const long mBase = (long)blockIdx.y * 128;
  const long nBase = (long)blockIdx.x * 128;

  f32x4 acc[4][4] = {};

  for (int k0 = 0; k0 < K; k0 += 64) {
    __syncthreads();
#pragma unroll
    for (int it = 0; it < 4; it++) {
      int idx = it * 256 + wave * 64 + lane;  // 16B-chunk index 0..1023
      int row = idx >> 3;
      int kc = idx & 7;
      int skc = kc ^ (row & 7);               // pre-swizzled global source
      const unsigned short* ga = A + (mBase + row) * (long)K + k0 + skc * 8;
      const unsigned short* gb = B + (nBase + row) * (long)K + k0 + skc * 8;
      int lbase = (it * 256 + wave * 64) * 8; // wave-uniform LDS base (shorts)
      GL2LDS(ga, &lA[lbase]);
      GL2LDS(gb, &lB[lbase]);
    }
    __syncthreads();
#pragma unroll
    for (int kb = 0; kb < 2; kb++) {
      short8 af[4], bfr[4];
#pragma unroll
      for (int mt = 0; mt < 4; mt++) {
        int row = wr * 64 + mt * 16 + (lane & 15);
        int slot = (kb * 4 + (lane >> 4)) ^ (row & 7);
        af[mt] = *(const short8*)&lA[row * 64 + slot * 8];
      }
#pragma unroll
      for (int nt = 0; nt < 4; nt++) {
        int row = wc * 64 + nt * 16 + (lane & 15);
        int slot = (kb * 4 + (lane >> 4)) ^ (row & 7);
        bfr[nt] = *(const short8*)&lB[row * 64 + slot * 8];
      }
#pragma unroll
      for (int mt = 0; mt < 4; mt++)
#pragma unroll
        for (int nt = 0; nt < 4; nt++)
          acc[mt][nt] = __builtin_amdgcn_mfma_f32_16x16x32_bf16(af[mt], bfr[nt], acc[mt][nt], 0, 0, 0);
    }
  }
#pragma unroll
  for (int mt = 0; mt < 4; mt++) {
#pragma unroll
    for (int nt = 0; nt < 4; nt++) {
#pragma unroll
      for (int j = 0; j < 4; j++) {
        long row = mBase + wr * 64 + mt * 16 + (lane >> 4) * 4 + j;
        long col = nBase + wc * 64 + nt * 16 + (lane & 15);
        float v = acc[mt][nt][j];
        if constexpr (RES) v = resid[row * (long)N + col] + fmaxf(v, 0.0f);
        C[row * (long)N + col] = f2bf(v);
      }
    }
  }
}

// ---------------- per-group inner attention ---------------------------------
__global__ __launch_bounds__(256) void k_attn_inner(const unsigned short* __restrict__ fe,
                                                    const unsigned short* __restrict__ topkb,
                                                    unsigned short* __restrict__ agg) {
  __shared__ unsigned short attb[128 * 136];
  __shared__ unsigned short featT[64 * 128];  // [c'][l], l XOR-swizzled by (c'>>3)
  __shared__ float redmax[2 * 128];
  __shared__ float redsum[2 * 128];
  const int tid = threadIdx.x;
  const int lane = tid & 63;
  const int wave = tid >> 6;
  const int wr = wave >> 1, wc = wave & 1;
  const int g = blockIdx.x;
  const unsigned short* feG = fe + (long)g * 128 * 256;

  // ---- Phase 1: S = fe * fe^T (frags straight from global; L2-hot)
  f32x4 s[4][4] = {};
#pragma unroll
  for (int kb = 0; kb < 8; kb++) {
    short8 af[4], bfr[4];
#pragma unroll
    for (int mt = 0; mt < 4; mt++) {
      int row = wr * 64 + mt * 16 + (lane & 15);
      af[mt] = *(const short8*)(feG + row * 256 + kb * 32 + (lane >> 4) * 8);
    }
#pragma unroll
    for (int nt = 0; nt < 4; nt++) {
      int row = wc * 64 + nt * 16 + (lane & 15);
      bfr[nt] = *(const short8*)(feG + row * 256 + kb * 32 + (lane >> 4) * 8);
    }
#pragma unroll
    for (int mt = 0; mt < 4; mt++)
#pragma unroll
      for (int nt = 0; nt < 4; nt++)
        s[mt][nt] = __builtin_amdgcn_mfma_f32_16x16x32_bf16(af[mt], bfr[nt], s[mt][nt], 0, 0, 0);
  }

  // ---- softmax over columns
  const float cexp = 0.0625f * 1.44269504088896f;
#pragma unroll
  for (int mt = 0; mt < 4; mt++) {
#pragma unroll
    for (int j = 0; j < 4; j++) {
      float m = fmaxf(fmaxf(s[mt][0][j], s[mt][1][j]), fmaxf(s[mt][2][j], s[mt][3][j]));
#pragma unroll
      for (int d = 1; d < 16; d <<= 1) m = fmaxf(m, __shfl_xor(m, d, 64));
      int r = wr * 64 + mt * 16 + (lane >> 4) * 4 + j;
      if ((lane & 15) == 0) redmax[wc * 128 + r] = m;
    }
  }
  __syncthreads();
#pragma unroll
  for (int mt = 0; mt < 4; mt++) {
#pragma unroll
    for (int j = 0; j < 4; j++) {
      int r = wr * 64 + mt * 16 + (lane >> 4) * 4 + j;
      float M = fmaxf(redmax[r], redmax[128 + r]);
      float sm = 0.f;
#pragma unroll
      for (int nt = 0; nt < 4; nt++) {
        float p = exp2f((s[mt][nt][j] - M) * cexp);
        s[mt][nt][j] = p;
        sm += p;
      }
#pragma unroll
      for (int d = 1; d < 16; d <<= 1) sm += __shfl_xor(sm, d, 64);
      if ((lane & 15) == 0) redsum[wc * 128 + r] = sm;
    }
  }
  __syncthreads();
#pragma unroll
  for (int mt = 0; mt < 4; mt++) {
#pragma unroll
    for (int j = 0; j < 4; j++) {
      int r = wr * 64 + mt * 16 + (lane >> 4) * 4 + j;
      float inv = 1.0f / (redsum[r] + redsum[128 + r]);
#pragma unroll
      for (int nt = 0; nt < 4; nt++) {
        int c = wc * 64 + nt * 16 + (lane & 15);
        attb[r * 136 + c] = f2bf(s[mt][nt][j] * inv);
      }
    }
  }

  // ---- Phase 2: agg = att @ feat, 64-col chunks, transposed LDS tile
  for (int ch = 0; ch < 32; ch++) {
    __syncthreads();
#pragma unroll
    for (int i = 0; i < 4; i++) {
      int seg = i * 256 + tid;
      int l = seg >> 3, kc = seg & 7;
      const unsigned short* gp = topkb + ((long)g * 128 + l) * 2048 + ch * 64 + kc * 8;
      uint4 w = *(const uint4*)gp;
      unsigned short v[8];
      v[0] = (unsigned short)(w.x & 0xffff); v[1] = (unsigned short)(w.x >> 16);
      v[2] = (unsigned short)(w.y & 0xffff); v[3] = (unsigned short)(w.y >> 16);
      v[4] = (unsigned short)(w.z & 0xffff); v[5] = (unsigned short)(w.z >> 16);
      v[6] = (unsigned short)(w.w & 0xffff); v[7] = (unsigned short)(w.w >> 16);
      int lx = l ^ (kc << 3);
#pragma unroll
      for (int j = 0; j < 8; j++) featT[(kc * 8 + j) * 128 + lx] = v[j];
    }
    __syncthreads();
    f32x4 c[2][4] = {};
#pragma unroll
    for (int kb = 0; kb < 4; kb++) {
      short8 af2[2], bf2v[4];
#pragma unroll
      for (int mt = 0; mt < 2; mt++) {
        int r = wave * 32 + mt * 16 + (lane & 15);
        af2[mt] = *(const short8*)&attb[r * 136 + kb * 32 + (lane >> 4) * 8];
      }
#pragma unroll
      for (int nt = 0; nt < 4; nt++) {
        int cc = nt * 16 + (lane & 15);
        int l0 = (kb * 32 + (lane >> 4) * 8) ^ (((cc >> 3) & 7) << 3);
        bf2v[nt] = *(const short8*)&featT[cc * 128 + l0];
      }
#pragma unroll
      for (int mt = 0; mt < 2; mt++)
#pragma unroll
        for (int nt = 0; nt < 4; nt++)
          c[mt][nt] = __builtin_amdgcn_mfma_f32_16x16x32_bf16(af2[mt], bf2v[nt], c[mt][nt], 0, 0, 0);
    }
#pragma unroll
    for (int mt = 0; mt < 2; mt++)
#pragma unroll
      for (int nt = 0; nt < 4; nt++)
#pragma unroll
        for (int j = 0; j < 4; j++) {
          long row = (long)g * 128 + wave * 32 + mt * 16 + (lane >> 4) * 4 + j;
          int col = ch * 64 + nt * 16 + (lane & 15);
          agg[row * 2048 + col] = f2bf(c[mt][nt][j]);
        }
  }
}

// ---------------- pe = protos @ wi2^T  [20,5,256] ---------------------------
__global__ __launch_bounds__(256) void k_pe(const float* __restrict__ protos,
                                            const float* __restrict__ wi2,
                                            float* __restrict__ pe) {
  int n = blockIdx.x, oc = blockIdx.y, tid = threadIdx.x;
  if (tid < 160) {
    int p = tid >> 5, o = oc * 32 + (tid & 31);
    const float* pr = protos + ((long)n * 5 + p) * 2048;
    const float* wr = wi2 + (long)o * 2048;
    float acc = 0.f;
    for (int cidx = 0; cidx < 2048; cidx += 4) {
      float4 a = *(const float4*)(pr + cidx);
      float4 b = *(const float4*)(wr + cidx);
      acc += a.x * b.x + a.y * b.y + a.z * b.z + a.w * b.w;
    }
    pe[((long)n * 5 + p) * 256 + o] = acc;
  }
}

// ---------------- lg[n,p,m] = (pe[n,p,:] . fae[n,m,:]) * scale --------------
__global__ __launch_bounds__(256) void k_logits(const float* __restrict__ pe,
                                                const unsigned short* __restrict__ fae,
                                                float* __restrict__ lg) {
  __shared__ float pel[5 * 256];
  int n = blockIdx.x, mc = blockIdx.y, tid = threadIdx.x;
  for (int i = tid; i < 1280; i += 256) pel[i] = pe[(long)n * 1280 + i];
  __syncthreads();
  int m = mc * 256 + tid;
  const unsigned short* fr = fae + ((long)n * 2048 + m) * 256;
  float a[5] = {0.f, 0.f, 0.f, 0.f, 0.f};
  for (int o = 0; o < 256; o += 8) {
    uint4 w = *(const uint4*)(fr + o);
    float f[8];
    f[0] = bf2f((unsigned short)(w.x & 0xffff)); f[1] = bf2f((unsigned short)(w.x >> 16));
    f[2] = bf2f((unsigned short)(w.y & 0xffff)); f[3] = bf2f((unsigned short)(w.y >> 16));
    f[4] = bf2f((unsigned short)(w.z & 0xffff)); f[5] = bf2f((unsigned short)(w.z >> 16));
    f[6] = bf2f((unsigned short)(w.w & 0xffff)); f[7] = bf2f((unsigned short)(w.w >> 16));
#pragma unroll
    for (int j = 0; j < 8; j++) {
      float fv = f[j];
#pragma unroll
      for (int p = 0; p < 5; p++) a[p] += fv * pel[p * 256 + o + j];
    }
  }
#pragma unroll
  for (int p = 0; p < 5; p++) lg[((long)n * 5 + p) * 2048 + m] = a[p] * 0.0625f;
}

// ---------------- softmax over m (2048) per (n,p) ---------------------------
__global__ __launch_bounds__(256) void k_sm(const float* __restrict__ lg,
                                            float* __restrict__ att2) {
  __shared__ float red[4], red2[4];
  int b = blockIdx.x, tid = threadIdx.x;
  const float* src = lg + (long)b * 2048;
  float v[8];
  float mx = -1e30f;
#pragma unroll
  for (int i = 0; i < 8; i++) { v[i] = src[i * 256 + tid]; mx = fmaxf(mx, v[i]); }
#pragma unroll
  for (int d = 1; d < 64; d <<= 1) mx = fmaxf(mx, __shfl_xor(mx, d, 64));
  if ((tid & 63) == 0) red[tid >> 6] = mx;
  __syncthreads();
  mx = fmaxf(fmaxf(red[0], red[1]), fmaxf(red[2], red[3]));
  float sm = 0.f;
#pragma unroll
  for (int i = 0; i < 8; i++) { v[i] = exp2f((v[i] - mx) * 1.44269504088896f); sm += v[i]; }
#pragma unroll
  for (int d = 1; d < 64; d <<= 1) sm += __shfl_xor(sm, d, 64);
  if ((tid & 63) == 0) red2[tid >> 6] = sm;
  __syncthreads();
  float inv = 1.0f / (red2[0] + red2[1] + red2[2] + red2[3]);
  float* dst = att2 + (long)b * 2048;
#pragma unroll
  for (int i = 0; i < 8; i++) dst[i * 256 + tid] = v[i] * inv;
}

// ---------------- un_protos partials: att2 @ fa (m-split) -------------------
__global__ __launch_bounds__(256) void k_out_part(const float* __restrict__ att2,
                                                  const unsigned short* __restrict__ feats,
                                                  float* __restrict__ partial) {
  __shared__ float a2[5 * 512];
  int n = blockIdx.x, cb = blockIdx.y, ms = blockIdx.z;
  int tid = threadIdx.x;
  const float* src = att2 + (long)n * 5 * 2048 + ms * 512;
  for (int i = tid; i < 640; i += 256) {
    int p = i >> 7, q = i & 127;
    ((float4*)a2)[i] = *(const float4*)(src + p * 2048 + q * 4);
  }
  __syncthreads();
  int c0 = cb * 1024 + tid * 4;
  const unsigned short* fp = feats + ((long)n * 2048 + ms * 512) * 2048 + c0;
  float acc[5][4] = {};
  for (int m = 0; m < 512; m++) {
    uint2 w = *(const uint2*)(fp + (long)m * 2048);
    float f0 = bf2f((unsigned short)(w.x & 0xffff));
    float f1 = bf2f((unsigned short)(w.x >> 16));
    float f2 = bf2f((unsigned short)(w.y & 0xffff));
    float f3 = bf2f((unsigned short)(w.y >> 16));
#pragma unroll
    for (int p = 0; p < 5; p++) {
      float a = a2[p * 512 + m];
      acc[p][0] += a * f0; acc[p][1] += a * f1; acc[p][2] += a * f2; acc[p][3] += a * f3;
    }
  }
  float* pp = partial + ((long)ms * 100 + (long)n * 5) * 2048;
#pragma unroll
  for (int p = 0; p < 5; p++) {
    float4 o; o.x = acc[p][0]; o.y = acc[p][1]; o.z = acc[p][2]; o.w = acc[p][3];
    *(float4*)(pp + p * 2048 + c0) = o;
  }
}

__global__ __launch_bounds__(256) void k_out_red(const float* __restrict__ partial,
                                                 float* __restrict__ outp) {
  int i = blockIdx.x * 256 + threadIdx.x;  // float4 idx < 51200
  const f32x4* P = (const f32x4*)partial;
  f32x4 s = P[i] + P[51200 + i] + P[2 * 51200 + i] + P[3 * 51200 + i];
  ((f32x4*)outp)[i] = s;
}

extern "C" void kernel_launch(void* const* d_in, const int* in_sizes, int n_in,
                              void* d_out, int out_size, void* d_ws, size_t ws_size,
                              hipStream_t stream) {
  const float* topk = (const float*)d_in[0];
  const float* protos = (const float*)d_in[1];
  const float* w1 = (const float*)d_in[2];
  const float* wt = (const float*)d_in[3];
  const float* wi1 = (const float*)d_in[4];
  const float* wi2 = (const float*)d_in[5];
  float* outp = (float*)d_out;

  char* ws = (char*)d_ws;
  size_t off = 0;
  auto alloc = [&](size_t bytes) -> void* {
    void* p = ws + off;
    off += (bytes + 255) & ~(size_t)255;
    return p;
  };
  unsigned short* w1b = (unsigned short*)alloc((size_t)256 * 2048 * 2);
  unsigned short* wtb = (unsigned short*)alloc((size_t)2048 * 2048 * 2);
  unsigned short* wi1b = (unsigned short*)alloc((size_t)256 * 2048 * 2);
  unsigned short* topkb = (unsigned short*)alloc((size_t)40960 * 2048 * 2);  // aliased by feats
  unsigned short* fe = (unsigned short*)alloc((size_t)40960 * 256 * 2);      // aliased by fae
  unsigned short* agg = (unsigned short*)alloc((size_t)40960 * 2048 * 2);
  float* pe = (float*)alloc((size_t)20 * 5 * 256 * 4);
  float* lg = (float*)alloc((size_t)20 * 5 * 2048 * 4);
  float* att2 = (float*)alloc((size_t)20 * 5 * 2048 * 4);
  float* partial = (float*)alloc((size_t)4 * 20 * 5 * 2048 * 4);
  unsigned short* feats = topkb;  // topkb dead after attn; big GEMM writes here
  unsigned short* fae = fe;       // fe dead after attn

  k_cvt_bf16<<<512, 256, 0, stream>>>(w1, w1b, 131072);
  k_cvt_bf16<<<4096, 256, 0, stream>>>(wt, wtb, 1048576);
  k_cvt_bf16<<<512, 256, 0, stream>>>(wi1, wi1b, 131072);
  k_cvt_bf16<<<81920, 256, 0, stream>>>(topk, topkb, 20971520);

  // fe = topk @ W1^T
  k_gemm_bt<false><<<dim3(2, 320), 256, 0, stream>>>(topkb, w1b, fe, nullptr, 256);
  // inner attention -> agg
  k_attn_inner<<<320, 256, 0, stream>>>(fe, topkb, agg);
  // feats = topk + relu(agg @ Wt^T)   (resid stays f32)
  k_gemm_bt<true><<<dim3(16, 320), 256, 0, stream>>>(agg, wtb, feats, topk, 2048);
  // fae = feats @ Wi1^T
  k_gemm_bt<false><<<dim3(2, 320), 256, 0, stream>>>(feats, wi1b, fae, nullptr, 256);
  // inter attention
  k_pe<<<dim3(20, 8), 256, 0, stream>>>(protos, wi2, pe);
  k_logits<<<dim3(20, 8), 256, 0, stream>>>(pe, fae, lg);
  k_sm<<<100, 256, 0, stream>>>(lg, att2);
  // output
  k_out_part<<<dim3(20, 2, 4), 256, 0, stream>>>(att2, feats, partial);
  k_out_red<<<200, 256, 0, stream>>>(partial, outp);
}